// Round 9
// baseline (592.158 us; speedup 1.0000x reference)
//
#include <hip/hip_runtime.h>
#include <math.h>

// Geometry constants
#define HW   4096      // 64*64
#define NCH  896       // 128+256+512
#define NB   16        // batch

typedef float f4 __attribute__((ext_vector_type(4)));

__device__ __forceinline__ float gelu_exact(float x) {
    return 0.5f * x * (1.0f + erff(x * 0.70710678118654752440f));
}
__device__ __forceinline__ float sigmoidf_(float x) {
    return 1.0f / (1.0f + expf(-x));
}

// ---------------------------------------------------------------------------
// Kernel 1: per-(b,channel) sum / sumsq / max / min over the 64x64 plane.
// One WAVE per plane: 16 float4 loads per lane (deep MLP), butterfly reduce,
// no LDS / no syncthreads. grid = NB*NCH/4 blocks of 256 (4 waves = 4 planes).
// ---------------------------------------------------------------------------
__global__ __launch_bounds__(256) void stats_kernel(
    const float* __restrict__ d0, const float* __restrict__ d1,
    const float* __restrict__ d2,
    float* __restrict__ S, float* __restrict__ S2,
    float* __restrict__ MX, float* __restrict__ MN)
{
    const int wid  = (blockIdx.x << 2) + (threadIdx.x >> 6);   // plane id
    const int lane = threadIdx.x & 63;
    const int b = wid / NCH;
    const int C = wid - b * NCH;
    const float* src; int cl, dim;
    if (C < 128)      { src = d0; cl = C;       dim = 128; }
    else if (C < 384) { src = d1; cl = C - 128; dim = 256; }
    else              { src = d2; cl = C - 384; dim = 512; }
    const f4* p = (const f4*)(src + ((size_t)b * dim + cl) * HW);

    float s = 0.f, s2 = 0.f, mx = -INFINITY, mn = INFINITY;
    #pragma unroll
    for (int k = 0; k < 16; ++k) {
        f4 v = p[lane + (k << 6)];
        s  += v.x + v.y + v.z + v.w;
        s2 += v.x*v.x + v.y*v.y + v.z*v.z + v.w*v.w;
        mx = fmaxf(mx, fmaxf(fmaxf(v.x, v.y), fmaxf(v.z, v.w)));
        mn = fminf(mn, fminf(fminf(v.x, v.y), fminf(v.z, v.w)));
    }
    #pragma unroll
    for (int off = 32; off > 0; off >>= 1) {
        s  += __shfl_xor(s,  off);
        s2 += __shfl_xor(s2, off);
        mx  = fmaxf(mx, __shfl_xor(mx, off));
        mn  = fminf(mn, __shfl_xor(mn, off));
    }
    if (lane == 0) {
        S [wid] = s;
        S2[wid] = s2;
        MX[wid] = mx;
        MN[wid] = mn;
    }
}

// ---------------------------------------------------------------------------
// Kernel 2: one block per batch. Derives the final per-channel affine
// (AF, BF) entirely from per-channel stats — all GroupNorms, gate MLPs,
// ge/le MLPs and the router, in LDS. (Per-CU L1-fill-bound at ~12.5 us —
// restructure deferred as low-ROI.)
// ---------------------------------------------------------------------------
__global__ __launch_bounds__(256) void coeff_kernel(
    const float* __restrict__ S, const float* __restrict__ S2,
    const float* __restrict__ MX, const float* __restrict__ MN,
    const float* __restrict__ gn0w, const float* __restrict__ gn0b,
    const float* __restrict__ gn1w, const float* __restrict__ gn1b,
    const float* __restrict__ gn2w, const float* __restrict__ gn2b,
    const float* __restrict__ g0w1, const float* __restrict__ g0b1,
    const float* __restrict__ g0w2, const float* __restrict__ g0b2,
    const float* __restrict__ g1w1, const float* __restrict__ g1b1,
    const float* __restrict__ g1w2, const float* __restrict__ g1b2,
    const float* __restrict__ g2w1, const float* __restrict__ g2b1,
    const float* __restrict__ g2w2, const float* __restrict__ g2b2,
    const float* __restrict__ cnw,  const float* __restrict__ cnb,
    const float* __restrict__ gew1, const float* __restrict__ geb1,
    const float* __restrict__ gew2, const float* __restrict__ geb2,
    const float* __restrict__ lew1, const float* __restrict__ leb1,
    const float* __restrict__ lew2, const float* __restrict__ leb2,
    const float* __restrict__ rw,   const float* __restrict__ rb,
    const float* __restrict__ temp, const float* __restrict__ gamma,
    float* __restrict__ AF, float* __restrict__ BF)
{
    const int b = blockIdx.x;
    const int t = threadIdx.x;

    __shared__ float sS[NCH], sS2[NCH], sMX[NCH], sMN[NCH];
    __shared__ float sP[NCH], sG[NCH], sA[NCH], sB[NCH];
    __shared__ float sGP[NCH], sMP[NCH];
    __shared__ float sMu[96], sRs[96], sMu2[32], sRs2[32];
    __shared__ float sH[224];
    __shared__ float sLog[2];

    for (int c = t; c < NCH; c += 256) {
        sS [c] = S [b*NCH + c];
        sS2[c] = S2[b*NCH + c];
        sMX[c] = MX[b*NCH + c];
        sMN[c] = MN[b*NCH + c];
    }
    __syncthreads();

    // ---- input GroupNorm stats (3 inputs x 32 groups) ----
    if (t < 96) {
        const int i = t >> 5, g = t & 31;
        const int cpg = (i == 0) ? 4 : (i == 1) ? 8 : 16;
        const int off = (i == 0) ? 0 : (i == 1) ? 128 : 384;
        const int base = off + g * cpg;
        float ss = 0.f, ss2 = 0.f;
        for (int k = 0; k < cpg; ++k) { ss += sS[base + k]; ss2 += sS2[base + k]; }
        const float invN = 1.0f / (cpg * (float)HW);
        const float mu = ss * invN;
        const float var = ss2 * invN - mu * mu;
        sMu[t] = mu;
        sRs[t] = rsqrtf(var + 1e-5f);
    }
    __syncthreads();

    // ---- p = mean over HW of group-normed input, per channel ----
    for (int c = t; c < NCH; c += 256) {
        int i, cl, cpg; const float *gw, *gb;
        if (c < 128)      { i = 0; cl = c;       cpg = 4;  gw = gn0w; gb = gn0b; }
        else if (c < 384) { i = 1; cl = c - 128; cpg = 8;  gw = gn1w; gb = gn1b; }
        else              { i = 2; cl = c - 384; cpg = 16; gw = gn2w; gb = gn2b; }
        const int gi = (i << 5) + cl / cpg;
        sP[c] = (sS[c] * (1.0f / HW) - sMu[gi]) * sRs[gi] * gw[cl] + gb[cl];
    }
    __syncthreads();

    // ---- gate MLP hidden (32+64+128 = 224 units) ----
    if (t < 224) {
        int h, d, off; const float *w1, *b1;
        if (t < 32)      { h = t;      d = 128; off = 0;   w1 = g0w1; b1 = g0b1; }
        else if (t < 96) { h = t - 32; d = 256; off = 128; w1 = g1w1; b1 = g1b1; }
        else             { h = t - 96; d = 512; off = 384; w1 = g2w1; b1 = g2b1; }
        float acc = b1[h];
        const float* wr = w1 + (size_t)h * d;
        for (int c = 0; c < d; ++c) acc += sP[off + c] * wr[c];
        sH[t] = gelu_exact(acc);
    }
    __syncthreads();

    // ---- gate MLP out -> per-channel gate sigmoid ----
    for (int c = t; c < NCH; c += 256) {
        int cl, hid, hoff; const float *w2, *b2;
        if (c < 128)      { cl = c;       hid = 32;  hoff = 0;  w2 = g0w2; b2 = g0b2; }
        else if (c < 384) { cl = c - 128; hid = 64;  hoff = 32; w2 = g1w2; b2 = g1b2; }
        else              { cl = c - 384; hid = 128; hoff = 96; w2 = g2w2; b2 = g2b2; }
        float acc = b2[cl];
        const float* wr = w2 + (size_t)cl * hid;
        for (int u = 0; u < hid; ++u) acc += sH[hoff + u] * wr[u];
        sG[c] = sigmoidf_(acc);
    }
    __syncthreads();

    // ---- affine through gn+gate, then per-channel stats of gated y ----
    for (int c = t; c < NCH; c += 256) {
        int i, cl, cpg; const float *gw, *gb;
        if (c < 128)      { i = 0; cl = c;       cpg = 4;  gw = gn0w; gb = gn0b; }
        else if (c < 384) { i = 1; cl = c - 128; cpg = 8;  gw = gn1w; gb = gn1b; }
        else              { i = 2; cl = c - 384; cpg = 16; gw = gn2w; gb = gn2b; }
        const int gi = (i << 5) + cl / cpg;
        const float mu = sMu[gi], rs = sRs[gi];
        const float a0 = rs * gw[cl];
        const float gch = sG[c];
        const float A = a0 * gch;
        const float B = (gb[cl] - mu * a0) * gch;
        sA[c] = A; sB[c] = B;
        const float s1 = sS[c], s2v = sS2[c];
        sP[c] = A * s1 + B * (float)HW;                                // Σy
        sG[c] = A * A * s2v + 2.0f * A * B * s1 + B * B * (float)HW;   // Σy²
    }
    __syncthreads();

    // ---- concat GroupNorm stats (32 groups of 28 channels) ----
    if (t < 32) {
        float ss = 0.f, ss2 = 0.f;
        const int base = t * 28;
        for (int k = 0; k < 28; ++k) { ss += sP[base + k]; ss2 += sG[base + k]; }
        const float invN = 1.0f / (28.0f * (float)HW);
        const float mu = ss * invN;
        const float var = ss2 * invN - mu * mu;
        sMu2[t] = mu;
        sRs2[t] = rsqrtf(var + 1e-5f);
    }
    __syncthreads();

    // ---- final affine (A2,B2); gp (mean pool) and mp (max pool) ----
    for (int c = t; c < NCH; c += 256) {
        const int g2 = c / 28;
        const float mu2 = sMu2[g2], rs2 = sRs2[g2];
        const float w = cnw[c] * rs2;
        const float a2 = sA[c] * w;
        const float b2v = (sB[c] - mu2) * w + cnb[c];
        sA[c] = a2; sB[c] = b2v;
        sGP[c] = a2 * (sS[c] * (1.0f / HW)) + b2v;
        sMP[c] = (a2 >= 0.f) ? (a2 * sMX[c] + b2v) : (a2 * sMN[c] + b2v);
    }
    __syncthreads();

    // ---- ge/le hidden layers (112 each) + router logits ----
    if (t < 224) {
        int q; const float *w1, *b1, *src;
        if (t < 112) { q = t;       w1 = gew1; b1 = geb1; src = sGP; }
        else         { q = t - 112; w1 = lew1; b1 = leb1; src = sMP; }
        float acc = b1[q];
        const float* wr = w1 + (size_t)q * NCH;
        for (int c = 0; c < NCH; ++c) acc += src[c] * wr[c];
        sH[t] = gelu_exact(acc);
    }
    if (t == 224 || t == 225) {
        const int r = t - 224;
        float acc = rb[r];
        const float* wr = rw + r * NCH;
        for (int c = 0; c < NCH; ++c) acc += sGP[c] * wr[c];
        sLog[r] = acc;
    }
    __syncthreads();

    // ---- softmax router, second MLP layers, final AF/BF ----
    const float tclip = fminf(fmaxf(temp[0], 0.5f), 2.0f);
    const float invt = 1.0f / tclip;
    const float l0 = sLog[0], l1 = sLog[1];
    const float m = fmaxf(l0, l1);
    const float e0 = expf(l0 - m), e1 = expf(l1 - m);
    const float alpha = e0 / (e0 + e1), beta = e1 / (e0 + e1);
    const float gam = gamma[0];
    for (int c = t; c < NCH; c += 256) {
        float accg = geb2[c], accl = leb2[c];
        const float* wgr = gew2 + (size_t)c * 112;
        const float* wlr = lew2 + (size_t)c * 112;
        for (int u = 0; u < 112; ++u) {
            accg += sH[u]       * wgr[u];
            accl += sH[112 + u] * wlr[u];
        }
        const float wgv = sigmoidf_(accg * invt);
        const float wlv = sigmoidf_(accl * invt);
        const float wch = alpha * wgv + beta * wlv * wgv;
        const float sc = wch + gam;
        AF[b*NCH + c] = sA[c] * sc;
        BF[b*NCH + c] = sB[c] * sc;
    }
}

// ---------------------------------------------------------------------------
// Kernel 3: out[b,C,:] = raw[b,C,:] * AF[b,C] + BF[b,C]
// One WAVE per plane, 16 float4 loads+stores per lane. Nontemporal loads
// (read-once) and stores (write-once) to keep L3 holding the input stream.
// ---------------------------------------------------------------------------
__global__ __launch_bounds__(256) void apply_kernel(
    const float* __restrict__ d0, const float* __restrict__ d1,
    const float* __restrict__ d2,
    const float* __restrict__ AF, const float* __restrict__ BF,
    float* __restrict__ out)
{
    const int wid  = (blockIdx.x << 2) + (threadIdx.x >> 6);   // plane id
    const int lane = threadIdx.x & 63;
    const int b = wid / NCH;
    const int C = wid - b * NCH;
    const float* src; int cl, dim;
    if (C < 128)      { src = d0; cl = C;       dim = 128; }
    else if (C < 384) { src = d1; cl = C - 128; dim = 256; }
    else              { src = d2; cl = C - 384; dim = 512; }
    const f4* pin = (const f4*)(src + ((size_t)b * dim + cl) * HW);
    f4* pout = (f4*)(out + (size_t)wid * HW);
    const float a  = AF[wid];
    const float bb = BF[wid];
    #pragma unroll
    for (int k = 0; k < 16; ++k) {
        f4 v = __builtin_nontemporal_load(&pin[lane + (k << 6)]);
        v = v * a + bb;
        __builtin_nontemporal_store(v, &pout[lane + (k << 6)]);
    }
}

extern "C" void kernel_launch(void* const* d_in, const int* in_sizes, int n_in,
                              void* d_out, int out_size, void* d_ws, size_t ws_size,
                              hipStream_t stream) {
    const float* d0   = (const float*)d_in[0];
    const float* d1   = (const float*)d_in[1];
    const float* d2   = (const float*)d_in[2];
    const float* gn0w = (const float*)d_in[3];
    const float* gn0b = (const float*)d_in[4];
    const float* g0w1 = (const float*)d_in[5];
    const float* g0b1 = (const float*)d_in[6];
    const float* g0w2 = (const float*)d_in[7];
    const float* g0b2 = (const float*)d_in[8];
    const float* gn1w = (const float*)d_in[9];
    const float* gn1b = (const float*)d_in[10];
    const float* g1w1 = (const float*)d_in[11];
    const float* g1b1 = (const float*)d_in[12];
    const float* g1w2 = (const float*)d_in[13];
    const float* g1b2 = (const float*)d_in[14];
    const float* gn2w = (const float*)d_in[15];
    const float* gn2b = (const float*)d_in[16];
    const float* g2w1 = (const float*)d_in[17];
    const float* g2b1 = (const float*)d_in[18];
    const float* g2w2 = (const float*)d_in[19];
    const float* g2b2 = (const float*)d_in[20];
    const float* cnw  = (const float*)d_in[21];
    const float* cnb  = (const float*)d_in[22];
    const float* gew1 = (const float*)d_in[23];
    const float* geb1 = (const float*)d_in[24];
    const float* gew2 = (const float*)d_in[25];
    const float* geb2 = (const float*)d_in[26];
    const float* lew1 = (const float*)d_in[27];
    const float* leb1 = (const float*)d_in[28];
    const float* lew2 = (const float*)d_in[29];
    const float* leb2 = (const float*)d_in[30];
    const float* rw   = (const float*)d_in[31];
    const float* rb   = (const float*)d_in[32];
    const float* temp = (const float*)d_in[33];
    const float* gamma= (const float*)d_in[34];

    float* S  = (float*)d_ws;
    float* S2 = S  + NB * NCH;
    float* MX = S2 + NB * NCH;
    float* MN = MX + NB * NCH;
    float* AF = MN + NB * NCH;
    float* BF = AF + NB * NCH;

    stats_kernel<<<(NB * NCH) / 4, 256, 0, stream>>>(d0, d1, d2, S, S2, MX, MN);
    coeff_kernel<<<NB, 256, 0, stream>>>(
        S, S2, MX, MN,
        gn0w, gn0b, gn1w, gn1b, gn2w, gn2b,
        g0w1, g0b1, g0w2, g0b2,
        g1w1, g1b1, g1w2, g1b2,
        g2w1, g2b1, g2w2, g2b2,
        cnw, cnb,
        gew1, geb1, gew2, geb2,
        lew1, leb1, lew2, leb2,
        rw, rb, temp, gamma, AF, BF);
    apply_kernel<<<(NB * NCH) / 4, 256, 0, stream>>>(d0, d1, d2, AF, BF, (float*)d_out);
}

// Round 12
// 553.036 us; speedup vs baseline: 1.0707x; 1.0707x over previous
//
#include <hip/hip_runtime.h>
#include <math.h>

// Geometry constants
#define HW   4096      // 64*64
#define NCH  896       // 128+256+512
#define NB   16        // batch

typedef float f4 __attribute__((ext_vector_type(4)));

__device__ __forceinline__ float gelu_exact(float x) {
    return 0.5f * x * (1.0f + erff(x * 0.70710678118654752440f));
}
__device__ __forceinline__ float sigmoidf_(float x) {
    return 1.0f / (1.0f + expf(-x));
}

// ---------------------------------------------------------------------------
// Kernel 1: per-(b,channel) sum / sumsq / max / min over the 64x64 plane.
// One WAVE per plane: 16 float4 loads per lane, butterfly reduce, no LDS.
// ---------------------------------------------------------------------------
__global__ __launch_bounds__(256) void stats_kernel(
    const float* __restrict__ d0, const float* __restrict__ d1,
    const float* __restrict__ d2,
    float* __restrict__ S, float* __restrict__ S2,
    float* __restrict__ MX, float* __restrict__ MN)
{
    const int wid  = (blockIdx.x << 2) + (threadIdx.x >> 6);   // plane id
    const int lane = threadIdx.x & 63;
    const int b = wid / NCH;
    const int C = wid - b * NCH;
    const float* src; int cl, dim;
    if (C < 128)      { src = d0; cl = C;       dim = 128; }
    else if (C < 384) { src = d1; cl = C - 128; dim = 256; }
    else              { src = d2; cl = C - 384; dim = 512; }
    const f4* p = (const f4*)(src + ((size_t)b * dim + cl) * HW);

    float s = 0.f, s2 = 0.f, mx = -INFINITY, mn = INFINITY;
    #pragma unroll
    for (int k = 0; k < 16; ++k) {
        f4 v = p[lane + (k << 6)];
        s  += v.x + v.y + v.z + v.w;
        s2 += v.x*v.x + v.y*v.y + v.z*v.z + v.w*v.w;
        mx = fmaxf(mx, fmaxf(fmaxf(v.x, v.y), fmaxf(v.z, v.w)));
        mn = fminf(mn, fminf(fminf(v.x, v.y), fminf(v.z, v.w)));
    }
    #pragma unroll
    for (int off = 32; off > 0; off >>= 1) {
        s  += __shfl_xor(s,  off);
        s2 += __shfl_xor(s2, off);
        mx  = fmaxf(mx, __shfl_xor(mx, off));
        mn  = fminf(mn, __shfl_xor(mn, off));
    }
    if (lane == 0) {
        S [wid] = s;
        S2[wid] = s2;
        MX[wid] = mx;
        MN[wid] = mn;
    }
}

// ---------------------------------------------------------------------------
// Kernel 2a: one block per batch. Input GroupNorms, gate MLPs, concat
// GroupNorm, final per-channel affine (wA,wB), gp/mp pools (wGP,wMP),
// router softmax (wAB). ge/le MLPs moved to coeffB1/B2 (they were 1.6 MB of
// the 2.2 MB per-block weight stream that made this kernel L1-fill-bound).
// NOTE: wA/wB/wGP/wMP alias S/S2/MX/MN (dead after the LDS staging at top) —
// those params are intentionally NOT __restrict__.
// ---------------------------------------------------------------------------
__global__ __launch_bounds__(256) void coeffA_kernel(
    const float* S, const float* S2,
    const float* MX, const float* MN,
    const float* __restrict__ gn0w, const float* __restrict__ gn0b,
    const float* __restrict__ gn1w, const float* __restrict__ gn1b,
    const float* __restrict__ gn2w, const float* __restrict__ gn2b,
    const float* __restrict__ g0w1, const float* __restrict__ g0b1,
    const float* __restrict__ g0w2, const float* __restrict__ g0b2,
    const float* __restrict__ g1w1, const float* __restrict__ g1b1,
    const float* __restrict__ g1w2, const float* __restrict__ g1b2,
    const float* __restrict__ g2w1, const float* __restrict__ g2b1,
    const float* __restrict__ g2w2, const float* __restrict__ g2b2,
    const float* __restrict__ cnw,  const float* __restrict__ cnb,
    const float* __restrict__ rw,   const float* __restrict__ rb,
    float* wA, float* wB, float* wGP, float* wMP,
    float* __restrict__ wAB)
{
    const int b = blockIdx.x;
    const int t = threadIdx.x;

    __shared__ float sS[NCH], sS2[NCH], sMX[NCH], sMN[NCH];
    __shared__ float sP[NCH], sG[NCH], sA[NCH], sB[NCH];
    __shared__ float sGP[NCH];
    __shared__ float sMu[96], sRs[96], sMu2[32], sRs2[32];
    __shared__ float sH[224];
    __shared__ float sLog[2];

    for (int c = t; c < NCH; c += 256) {
        sS [c] = S [b*NCH + c];
        sS2[c] = S2[b*NCH + c];
        sMX[c] = MX[b*NCH + c];
        sMN[c] = MN[b*NCH + c];
    }
    __syncthreads();

    // ---- input GroupNorm stats (3 inputs x 32 groups) ----
    if (t < 96) {
        const int i = t >> 5, g = t & 31;
        const int cpg = (i == 0) ? 4 : (i == 1) ? 8 : 16;
        const int off = (i == 0) ? 0 : (i == 1) ? 128 : 384;
        const int base = off + g * cpg;
        float ss = 0.f, ss2 = 0.f;
        for (int k = 0; k < cpg; ++k) { ss += sS[base + k]; ss2 += sS2[base + k]; }
        const float invN = 1.0f / (cpg * (float)HW);
        const float mu = ss * invN;
        const float var = ss2 * invN - mu * mu;
        sMu[t] = mu;
        sRs[t] = rsqrtf(var + 1e-5f);
    }
    __syncthreads();

    // ---- p = mean over HW of group-normed input, per channel ----
    for (int c = t; c < NCH; c += 256) {
        int i, cl, cpg; const float *gw, *gb;
        if (c < 128)      { i = 0; cl = c;       cpg = 4;  gw = gn0w; gb = gn0b; }
        else if (c < 384) { i = 1; cl = c - 128; cpg = 8;  gw = gn1w; gb = gn1b; }
        else              { i = 2; cl = c - 384; cpg = 16; gw = gn2w; gb = gn2b; }
        const int gi = (i << 5) + cl / cpg;
        sP[c] = (sS[c] * (1.0f / HW) - sMu[gi]) * sRs[gi] * gw[cl] + gb[cl];
    }
    __syncthreads();

    // ---- gate MLP hidden (32+64+128 = 224 units) ----
    if (t < 224) {
        int h, d, off; const float *w1, *b1;
        if (t < 32)      { h = t;      d = 128; off = 0;   w1 = g0w1; b1 = g0b1; }
        else if (t < 96) { h = t - 32; d = 256; off = 128; w1 = g1w1; b1 = g1b1; }
        else             { h = t - 96; d = 512; off = 384; w1 = g2w1; b1 = g2b1; }
        float acc = b1[h];
        const float* wr = w1 + (size_t)h * d;
        for (int c = 0; c < d; ++c) acc += sP[off + c] * wr[c];
        sH[t] = gelu_exact(acc);
    }
    __syncthreads();

    // ---- gate MLP out -> per-channel gate sigmoid ----
    for (int c = t; c < NCH; c += 256) {
        int cl, hid, hoff; const float *w2, *b2;
        if (c < 128)      { cl = c;       hid = 32;  hoff = 0;  w2 = g0w2; b2 = g0b2; }
        else if (c < 384) { cl = c - 128; hid = 64;  hoff = 32; w2 = g1w2; b2 = g1b2; }
        else              { cl = c - 384; hid = 128; hoff = 96; w2 = g2w2; b2 = g2b2; }
        float acc = b2[cl];
        const float* wr = w2 + (size_t)cl * hid;
        for (int u = 0; u < hid; ++u) acc += sH[hoff + u] * wr[u];
        sG[c] = sigmoidf_(acc);
    }
    __syncthreads();

    // ---- affine through gn+gate, then per-channel stats of gated y ----
    for (int c = t; c < NCH; c += 256) {
        int i, cl, cpg; const float *gw, *gb;
        if (c < 128)      { i = 0; cl = c;       cpg = 4;  gw = gn0w; gb = gn0b; }
        else if (c < 384) { i = 1; cl = c - 128; cpg = 8;  gw = gn1w; gb = gn1b; }
        else              { i = 2; cl = c - 384; cpg = 16; gw = gn2w; gb = gn2b; }
        const int gi = (i << 5) + cl / cpg;
        const float mu = sMu[gi], rs = sRs[gi];
        const float a0 = rs * gw[cl];
        const float gch = sG[c];
        const float A = a0 * gch;
        const float B = (gb[cl] - mu * a0) * gch;
        sA[c] = A; sB[c] = B;
        const float s1 = sS[c], s2v = sS2[c];
        sP[c] = A * s1 + B * (float)HW;                                // Σy
        sG[c] = A * A * s2v + 2.0f * A * B * s1 + B * B * (float)HW;   // Σy²
    }
    __syncthreads();

    // ---- concat GroupNorm stats (32 groups of 28 channels) ----
    if (t < 32) {
        float ss = 0.f, ss2 = 0.f;
        const int base = t * 28;
        for (int k = 0; k < 28; ++k) { ss += sP[base + k]; ss2 += sG[base + k]; }
        const float invN = 1.0f / (28.0f * (float)HW);
        const float mu = ss * invN;
        const float var = ss2 * invN - mu * mu;
        sMu2[t] = mu;
        sRs2[t] = rsqrtf(var + 1e-5f);
    }
    __syncthreads();

    // ---- final affine (A2,B2); gp (mean) / mp (max) pools; global writes ----
    for (int c = t; c < NCH; c += 256) {
        const int g2 = c / 28;
        const float mu2 = sMu2[g2], rs2 = sRs2[g2];
        const float w = cnw[c] * rs2;
        const float a2 = sA[c] * w;
        const float b2v = (sB[c] - mu2) * w + cnb[c];
        const float gp = a2 * (sS[c] * (1.0f / HW)) + b2v;
        const float mp = (a2 >= 0.f) ? (a2 * sMX[c] + b2v) : (a2 * sMN[c] + b2v);
        sGP[c] = gp;
        wA [b*NCH + c] = a2;     // aliases S  (dead: staged in LDS above)
        wB [b*NCH + c] = b2v;    // aliases S2
        wGP[b*NCH + c] = gp;     // aliases MX
        wMP[b*NCH + c] = mp;     // aliases MN
    }
    __syncthreads();

    // ---- router logits + softmax ----
    if (t == 0 || t == 1) {
        float acc = rb[t];
        const float* wr = rw + t * NCH;
        for (int c = 0; c < NCH; ++c) acc += sGP[c] * wr[c];
        sLog[t] = acc;
    }
    __syncthreads();
    if (t == 0) {
        const float l0 = sLog[0], l1 = sLog[1];
        const float m = fmaxf(l0, l1);
        const float e0 = expf(l0 - m), e1 = expf(l1 - m);
        wAB[b*2 + 0] = e0 / (e0 + e1);   // alpha
        wAB[b*2 + 1] = e1 / (e0 + e1);   // beta
    }
}

// ---------------------------------------------------------------------------
// Kernel 2b: ge/le hidden layers. grid = NB*7 blocks; each block computes 32
// of the 224 hidden units for one batch (8 threads per unit, shfl-tree
// reduce). Weight slice per block: 32x896x4 = 115 KB -> parallel L1 streams
// across 112 CUs instead of 16.
// ---------------------------------------------------------------------------
__global__ __launch_bounds__(256) void coeffB1_kernel(
    const float* __restrict__ wGP, const float* __restrict__ wMP,
    const float* __restrict__ gew1, const float* __restrict__ geb1,
    const float* __restrict__ lew1, const float* __restrict__ leb1,
    float* __restrict__ wH)
{
    const int b = blockIdx.x / 7;
    const int j = blockIdx.x - b * 7;
    const int t = threadIdx.x;
    __shared__ float sGPl[NCH], sMPl[NCH];
    for (int c = t; c < NCH; c += 256) {
        sGPl[c] = wGP[b*NCH + c];
        sMPl[c] = wMP[b*NCH + c];
    }
    __syncthreads();

    const int g = t >> 3;          // unit-in-block 0..31
    const int i = t & 7;           // lane-in-group 0..7
    const int unit = j * 32 + g;   // 0..223
    const float* srcv; const float* w1; const float* b1; int q;
    if (unit < 112) { q = unit;       srcv = sGPl; w1 = gew1; b1 = geb1; }
    else            { q = unit - 112; srcv = sMPl; w1 = lew1; b1 = leb1; }
    const float* wr = w1 + (size_t)q * NCH;

    float acc = 0.f;
    #pragma unroll 4
    for (int cc = 0; cc < 112; ++cc) {
        const int c = (cc << 3) + i;
        acc += srcv[c] * wr[c];
    }
    acc += __shfl_down(acc, 4, 8);
    acc += __shfl_down(acc, 2, 8);
    acc += __shfl_down(acc, 1, 8);
    if (i == 0) wH[b*224 + unit] = gelu_exact(acc + b1[q]);
}

// ---------------------------------------------------------------------------
// Kernel 2c: ge/le second layers + final AF/BF. grid = NB*7 blocks; each
// block handles 128 channels of one batch (115 KB weight slice).
// ---------------------------------------------------------------------------
__global__ __launch_bounds__(256) void coeffB2_kernel(
    const float* __restrict__ wA,  const float* __restrict__ wB,
    const float* __restrict__ wH,  const float* __restrict__ wAB,
    const float* __restrict__ gew2, const float* __restrict__ geb2,
    const float* __restrict__ lew2, const float* __restrict__ leb2,
    const float* __restrict__ temp, const float* __restrict__ gamma,
    float* __restrict__ AF, float* __restrict__ BF)
{
    const int b = blockIdx.x / 7;
    const int j = blockIdx.x - b * 7;
    const int t = threadIdx.x;
    __shared__ float sHl[224];
    if (t < 224) sHl[t] = wH[b*224 + t];
    __syncthreads();

    if (t < 128) {
        const int c = j * 128 + t;
        const float tclip = fminf(fmaxf(temp[0], 0.5f), 2.0f);
        const float invt = 1.0f / tclip;
        const float alpha = wAB[b*2 + 0];
        const float beta  = wAB[b*2 + 1];
        float accg = geb2[c], accl = leb2[c];
        const float* wgr = gew2 + (size_t)c * 112;
        const float* wlr = lew2 + (size_t)c * 112;
        #pragma unroll 4
        for (int u = 0; u < 112; ++u) {
            accg += sHl[u]       * wgr[u];
            accl += sHl[112 + u] * wlr[u];
        }
        const float wgv = sigmoidf_(accg * invt);
        const float wlv = sigmoidf_(accl * invt);
        const float wch = alpha * wgv + beta * wlv * wgv;
        const float sc = wch + gamma[0];
        AF[b*NCH + c] = wA[b*NCH + c] * sc;
        BF[b*NCH + c] = wB[b*NCH + c] * sc;
    }
}

// ---------------------------------------------------------------------------
// Kernel 3: out[b,C,:] = raw[b,C,:] * AF[b,C] + BF[b,C]
// One WAVE per plane; nontemporal loads (read-once) and stores (write-once).
// ---------------------------------------------------------------------------
__global__ __launch_bounds__(256) void apply_kernel(
    const float* __restrict__ d0, const float* __restrict__ d1,
    const float* __restrict__ d2,
    const float* __restrict__ AF, const float* __restrict__ BF,
    float* __restrict__ out)
{
    const int wid  = (blockIdx.x << 2) + (threadIdx.x >> 6);   // plane id
    const int lane = threadIdx.x & 63;
    const int b = wid / NCH;
    const int C = wid - b * NCH;
    const float* src; int cl, dim;
    if (C < 128)      { src = d0; cl = C;       dim = 128; }
    else if (C < 384) { src = d1; cl = C - 128; dim = 256; }
    else              { src = d2; cl = C - 384; dim = 512; }
    const f4* pin = (const f4*)(src + ((size_t)b * dim + cl) * HW);
    f4* pout = (f4*)(out + (size_t)wid * HW);
    const float a  = AF[wid];
    const float bb = BF[wid];
    #pragma unroll
    for (int k = 0; k < 16; ++k) {
        f4 v = __builtin_nontemporal_load(&pin[lane + (k << 6)]);
        v = v * a + bb;
        __builtin_nontemporal_store(v, &pout[lane + (k << 6)]);
    }
}

extern "C" void kernel_launch(void* const* d_in, const int* in_sizes, int n_in,
                              void* d_out, int out_size, void* d_ws, size_t ws_size,
                              hipStream_t stream) {
    const float* d0   = (const float*)d_in[0];
    const float* d1   = (const float*)d_in[1];
    const float* d2   = (const float*)d_in[2];
    const float* gn0w = (const float*)d_in[3];
    const float* gn0b = (const float*)d_in[4];
    const float* g0w1 = (const float*)d_in[5];
    const float* g0b1 = (const float*)d_in[6];
    const float* g0w2 = (const float*)d_in[7];
    const float* g0b2 = (const float*)d_in[8];
    const float* gn1w = (const float*)d_in[9];
    const float* gn1b = (const float*)d_in[10];
    const float* g1w1 = (const float*)d_in[11];
    const float* g1b1 = (const float*)d_in[12];
    const float* g1w2 = (const float*)d_in[13];
    const float* g1b2 = (const float*)d_in[14];
    const float* gn2w = (const float*)d_in[15];
    const float* gn2b = (const float*)d_in[16];
    const float* g2w1 = (const float*)d_in[17];
    const float* g2b1 = (const float*)d_in[18];
    const float* g2w2 = (const float*)d_in[19];
    const float* g2b2 = (const float*)d_in[20];
    const float* cnw  = (const float*)d_in[21];
    const float* cnb  = (const float*)d_in[22];
    const float* gew1 = (const float*)d_in[23];
    const float* geb1 = (const float*)d_in[24];
    const float* gew2 = (const float*)d_in[25];
    const float* geb2 = (const float*)d_in[26];
    const float* lew1 = (const float*)d_in[27];
    const float* leb1 = (const float*)d_in[28];
    const float* lew2 = (const float*)d_in[29];
    const float* leb2 = (const float*)d_in[30];
    const float* rw   = (const float*)d_in[31];
    const float* rb   = (const float*)d_in[32];
    const float* temp = (const float*)d_in[33];
    const float* gamma= (const float*)d_in[34];

    const int N = NB * NCH;
    float* S  = (float*)d_ws;        // also wA after coeffA
    float* S2 = S  + N;              // also wB after coeffA
    float* MX = S2 + N;              // also wGP after coeffA
    float* MN = MX + N;              // also wMP after coeffA
    float* AF = MN + N;
    float* BF = AF + N;
    float* wH  = BF + N;             // NB*224
    float* wAB = wH + NB * 224;      // NB*2

    stats_kernel<<<(NB * NCH) / 4, 256, 0, stream>>>(d0, d1, d2, S, S2, MX, MN);
    coeffA_kernel<<<NB, 256, 0, stream>>>(
        S, S2, MX, MN,
        gn0w, gn0b, gn1w, gn1b, gn2w, gn2b,
        g0w1, g0b1, g0w2, g0b2,
        g1w1, g1b1, g1w2, g1b2,
        g2w1, g2b1, g2w2, g2b2,
        cnw, cnb, rw, rb,
        /*wA*/S, /*wB*/S2, /*wGP*/MX, /*wMP*/MN, wAB);
    coeffB1_kernel<<<NB * 7, 256, 0, stream>>>(
        /*wGP*/MX, /*wMP*/MN, gew1, geb1, lew1, leb1, wH);
    coeffB2_kernel<<<NB * 7, 256, 0, stream>>>(
        /*wA*/S, /*wB*/S2, wH, wAB, gew2, geb2, lew2, leb2, temp, gamma, AF, BF);
    apply_kernel<<<(NB * NCH) / 4, 256, 0, stream>>>(d0, d1, d2, AF, BF, (float*)d_out);
}